// Round 1
// baseline (221.625 us; speedup 1.0000x reference)
//
#include <hip/hip_runtime.h>
#include <math.h>

typedef _Float16 h8 __attribute__((ext_vector_type(8)));
typedef _Float16 h4 __attribute__((ext_vector_type(4)));
typedef float    f4 __attribute__((ext_vector_type(4)));

#define NHEADS 6
#define HDIM   32
#define NTOK   512
#define NTAB   43   // rel_idx = qsum - ksum + 21 in [0,42]

// ---------------- tiny dynamic position-bias MLP (43 rows x 3->12->12->12->6) ----
__device__ inline void ln_relu12(const float* x, float* t, const float* g, const float* b) {
  float mu = 0.f;
#pragma unroll
  for (int j = 0; j < 12; j++) mu += x[j];
  mu *= (1.f / 12.f);
  float var = 0.f;
#pragma unroll
  for (int j = 0; j < 12; j++) { float d = x[j] - mu; var += d * d; }
  var *= (1.f / 12.f);
  float inv = rsqrtf(var + 1e-5f);
#pragma unroll
  for (int j = 0; j < 12; j++) {
    float y = (x[j] - mu) * inv * g[j] + b[j];
    t[j] = y > 0.f ? y : 0.f;
  }
}

__device__ inline void mm12(const float* t, float* x, const float* w, const float* c) {
#pragma unroll
  for (int j = 0; j < 12; j++) {
    float acc = c[j];
#pragma unroll
    for (int i = 0; i < 12; i++) acc += t[i] * w[i * 12 + j];
    x[j] = acc;
  }
}

__global__ void pos_mlp_kernel(
    const float* __restrict__ pw, const float* __restrict__ pb,
    const float* __restrict__ g1, const float* __restrict__ b1,
    const float* __restrict__ w1, const float* __restrict__ c1,
    const float* __restrict__ g2, const float* __restrict__ b2,
    const float* __restrict__ w2, const float* __restrict__ c2,
    const float* __restrict__ g3, const float* __restrict__ b3,
    const float* __restrict__ w3, const float* __restrict__ c3,
    float* __restrict__ posb)
{
  const int r = threadIdx.x;
  if (r >= NTAB) return;
  // table row r (< 225 so ih==0): biases = (-7, r/15 - 7, r%15 - 7)
  const float bh = -7.0f;
  const float bw = (float)(r / 15) - 7.0f;
  const float bd = (float)(r % 15) - 7.0f;
  float x[12], t[12];
#pragma unroll
  for (int j = 0; j < 12; j++)
    x[j] = bh * pw[j] + bw * pw[12 + j] + bd * pw[24 + j] + pb[j];
  ln_relu12(x, t, g1, b1); mm12(t, x, w1, c1);
  ln_relu12(x, t, g2, b2); mm12(t, x, w2, c2);
  ln_relu12(x, t, g3, b3);
#pragma unroll
  for (int hd = 0; hd < NHEADS; hd++) {
    float acc = c3[hd];
#pragma unroll
    for (int i = 0; i < 12; i++) acc += t[i] * w3[i * NHEADS + hd];
    posb[r * NHEADS + hd] = acc;
  }
}

// ---------------- flash attention, fp16 MFMA 16x16x32 -----------------------------
// grid (8, 6, 64); block 256 (4 waves). Block: 64 queries of one (b,h).
// Wave w owns queries [q0 + 16w, q0 + 16w + 16). K/V chunks of 64 keys.
__global__ __launch_bounds__(256)
void attn_kernel(const float* __restrict__ qp, const float* __restrict__ kp,
                 const float* __restrict__ vp, const float* __restrict__ posb,
                 float* __restrict__ out)
{
  __shared__ _Float16 Qs[64 * 40];   // stride 40 halves = 80 B (16B-aligned rows)
  __shared__ _Float16 Ks[64 * 40];
  __shared__ _Float16 Vt[32 * 72];   // V transposed: Vt[c][key], stride 72 = 144 B
  __shared__ _Float16 Ps[64 * 72];   // per-wave 16 rows: D-layout -> A-layout round trip
  __shared__ float    posw[NTAB];

  const int tid  = threadIdx.x;
  const int wave = tid >> 6;
  const int lane = tid & 63;
  const int quad = lane >> 4;
  const int l16  = lane & 15;
  const int h    = blockIdx.y;
  const int b    = blockIdx.z;
  const int q0   = blockIdx.x * 64;
  const long bh_off = ((long)(b * NHEADS + h)) * NTOK * HDIM;

  if (tid < NTAB) posw[tid] = posb[tid * NHEADS + h];

  // ---- stage Q tile (64x32 fp32 -> fp16 LDS) ----
  {
    const float4* qg = (const float4*)(qp + bh_off + (long)q0 * HDIM);
    for (int f = tid; f < 512; f += 256) {
      int row = f >> 3, c4 = f & 7;
      float4 val = qg[row * 8 + c4];
      h4 hv = { (_Float16)val.x, (_Float16)val.y, (_Float16)val.z, (_Float16)val.w };
      *(h4*)&Qs[row * 40 + c4 * 4] = hv;
    }
  }
  __syncthreads();

  // A-frag: lane holds Q[m=l16][k=quad*8 + j]  (m120-verified A layout)
  const h8 qf = *(const h8*)&Qs[(wave * 16 + l16) * 40 + quad * 8];

  f4 o0 = {0.f, 0.f, 0.f, 0.f};
  f4 o1 = {0.f, 0.f, 0.f, 0.f};
  float m_[4], l_[4];
  int qs21[4];  // qsum + 21, rows quad*4 + r
#pragma unroll
  for (int r = 0; r < 4; r++) {
    m_[r] = -1e30f; l_[r] = 0.f;
    int qg_ = q0 + wave * 16 + quad * 4 + r;
    qs21[r] = (qg_ >> 6) + ((qg_ >> 3) & 7) + (qg_ & 7) + 21;
  }
  const float scale = 0.17677669529663687f;  // 32^-0.5

  for (int kc = 0; kc < 8; kc++) {
    const int k0 = kc * 64;
    __syncthreads();  // protect Ks/Vt from previous iteration's readers
    // ---- stage K chunk + transposed V chunk ----
    {
      const float4* kg = (const float4*)(kp + bh_off + (long)k0 * HDIM);
      const float4* vg = (const float4*)(vp + bh_off + (long)k0 * HDIM);
      for (int f = tid; f < 512; f += 256) {
        int row = f >> 3, c4 = f & 7;
        float4 val = kg[row * 8 + c4];
        h4 hv = { (_Float16)val.x, (_Float16)val.y, (_Float16)val.z, (_Float16)val.w };
        *(h4*)&Ks[row * 40 + c4 * 4] = hv;
        float4 vv = vg[row * 8 + c4];
        Vt[(c4 * 4 + 0) * 72 + row] = (_Float16)vv.x;
        Vt[(c4 * 4 + 1) * 72 + row] = (_Float16)vv.y;
        Vt[(c4 * 4 + 2) * 72 + row] = (_Float16)vv.z;
        Vt[(c4 * 4 + 3) * 72 + row] = (_Float16)vv.w;
      }
    }
    __syncthreads();

    // ---- S = Q @ K^T : 4 key tiles of 16. B-frag = K rows in A-layout pattern ----
    f4 s[4];
    const f4 zero = {0.f, 0.f, 0.f, 0.f};
#pragma unroll
    for (int t = 0; t < 4; t++) {
      h8 kf = *(const h8*)&Ks[(t * 16 + l16) * 40 + quad * 8];
      s[t] = __builtin_amdgcn_mfma_f32_16x16x32_f16(qf, kf, zero, 0, 0, 0);
    }
    // D layout: row = quad*4 + r (query), col = l16 (key within tile)
    // ---- scale + relative position bias ----
    int ks_[4];
#pragma unroll
    for (int t = 0; t < 4; t++) {
      int kgl = k0 + t * 16 + l16;
      ks_[t] = (kgl >> 6) + ((kgl >> 3) & 7) + (kgl & 7);
    }
#pragma unroll
    for (int t = 0; t < 4; t++)
#pragma unroll
      for (int r = 0; r < 4; r++)
        s[t][r] = s[t][r] * scale + posw[qs21[r] - ks_[t]];

    // ---- online softmax (state replicated across the 16 lanes of each quad) ----
    float mx[4];
#pragma unroll
    for (int r = 0; r < 4; r++) {
      float m0 = fmaxf(fmaxf(s[0][r], s[1][r]), fmaxf(s[2][r], s[3][r]));
#pragma unroll
      for (int d = 1; d < 16; d <<= 1) m0 = fmaxf(m0, __shfl_xor(m0, d));
      mx[r] = m0;
    }
    float al[4];
#pragma unroll
    for (int r = 0; r < 4; r++) {
      float mn = fmaxf(m_[r], mx[r]);
      al[r] = __expf(m_[r] - mn);
      m_[r] = mn;
    }
    float rs[4] = {0.f, 0.f, 0.f, 0.f};
#pragma unroll
    for (int t = 0; t < 4; t++)
#pragma unroll
      for (int r = 0; r < 4; r++) {
        float p = __expf(s[t][r] - m_[r]);
        rs[r] += p;
        Ps[(wave * 16 + quad * 4 + r) * 72 + t * 16 + l16] = (_Float16)p;
      }
#pragma unroll
    for (int r = 0; r < 4; r++) {
#pragma unroll
      for (int d = 1; d < 16; d <<= 1) rs[r] += __shfl_xor(rs[r], d);
      l_[r] = l_[r] * al[r] + rs[r];
      o0[r] *= al[r];
      o1[r] *= al[r];
    }

    // ---- O += P @ V : P re-read in A layout (same-wave LDS round trip),
    //      V B-frag from transposed LDS: lane holds V[k=quad*8+j][n=l16(+16)] ----
#pragma unroll
    for (int kt = 0; kt < 2; kt++) {
      h8 pf  = *(const h8*)&Ps[(wave * 16 + l16) * 72 + kt * 32 + quad * 8];
      h8 vf0 = *(const h8*)&Vt[(l16) * 72      + kt * 32 + quad * 8];
      h8 vf1 = *(const h8*)&Vt[(16 + l16) * 72 + kt * 32 + quad * 8];
      o0 = __builtin_amdgcn_mfma_f32_16x16x32_f16(pf, vf0, o0, 0, 0, 0);
      o1 = __builtin_amdgcn_mfma_f32_16x16x32_f16(pf, vf1, o1, 0, 0, 0);
    }
  }

  // ---- epilogue: normalize and store fp32 ----
#pragma unroll
  for (int r = 0; r < 4; r++) {
    float inv = 1.f / l_[r];
    long orow = bh_off + (long)(q0 + wave * 16 + quad * 4 + r) * HDIM;
    out[orow + l16]      = o0[r] * inv;
    out[orow + 16 + l16] = o1[r] * inv;
  }
}

extern "C" void kernel_launch(void* const* d_in, const int* in_sizes, int n_in,
                              void* d_out, int out_size, void* d_ws, size_t ws_size,
                              hipStream_t stream) {
  (void)in_sizes; (void)n_in; (void)out_size; (void)ws_size;
  const float* q  = (const float*)d_in[0];
  const float* k  = (const float*)d_in[1];
  const float* v  = (const float*)d_in[2];
  // d_in[3..5] = h,w,d scalars (always 8; hard-coded)
  const float* pw  = (const float*)d_in[6];
  const float* pb  = (const float*)d_in[7];
  const float* g1  = (const float*)d_in[8];
  const float* b1  = (const float*)d_in[9];
  const float* w1  = (const float*)d_in[10];
  const float* c1  = (const float*)d_in[11];
  const float* g2  = (const float*)d_in[12];
  const float* b2  = (const float*)d_in[13];
  const float* w2  = (const float*)d_in[14];
  const float* c2  = (const float*)d_in[15];
  const float* g3  = (const float*)d_in[16];
  const float* b3  = (const float*)d_in[17];
  const float* w3  = (const float*)d_in[18];
  const float* c3  = (const float*)d_in[19];
  float* posb = (float*)d_ws;          // 43*6 floats
  float* outp = (float*)d_out;

  pos_mlp_kernel<<<1, 64, 0, stream>>>(pw, pb, g1, b1, w1, c1, g2, b2, w2, c2,
                                       g3, b3, w3, c3, posb);
  attn_kernel<<<dim3(8, NHEADS, 64), 256, 0, stream>>>(q, k, v, posb, outp);
}